// Round 1
// baseline (1122.933 us; speedup 1.0000x reference)
//
#include <hip/hip_runtime.h>
#include <hip/hip_bf16.h>
#include <math.h>

// Problem constants (derived at launch where cheap, hardcoded in kernels):
//   E = 800000 edges, IN_DIM = 192, D_OUT = 64, N = out_size/64 = 50000
//
// Pipeline:
//   K0 init:      out=0, segmax=-inf, denom=0, W fp32 -> bf16
//   K1 gemm_att:  h = X @ W^T via bf16 MFMA (16x16x32), a = mish(h . w_att),
//                 atomic segment-max of a into segmax[dst]
//   K2 exp_denom: a[e] = exp(a[e]-segmax[dst]); denom[dst] += a[e]
//   K3 aggregate: out[dst,:] += h[e,:] * (a[e]/denom[dst])   (wave per edge)

typedef __bf16  bf16x8 __attribute__((ext_vector_type(8)));
typedef float   f32x4  __attribute__((ext_vector_type(4)));

#define KDIM 192
#define LDSS 200   // LDS row stride in bf16 units (padded; 400B, 16B-aligned)

__device__ inline unsigned short f2bf(float f) {
    unsigned u = __float_as_uint(f);
    unsigned r = u + 0x7fffu + ((u >> 16) & 1u);   // round-to-nearest-even
    return (unsigned short)(r >> 16);
}
__device__ inline float bf2f(unsigned short h) {
    return __uint_as_float(((unsigned)h) << 16);
}

__global__ void init_kernel(float* __restrict__ out, int out_n,
                            float* __restrict__ segmax, float* __restrict__ denom, int n_nodes,
                            const float* __restrict__ W, unsigned short* __restrict__ wbf, int wn) {
    int i = blockIdx.x * blockDim.x + threadIdx.x;
    int stride = gridDim.x * blockDim.x;
    for (int j = i; j < out_n; j += stride) out[j] = 0.0f;
    for (int j = i; j < n_nodes; j += stride) {
        ((unsigned*)segmax)[j] = 0xFF800000u;  // -inf
        denom[j] = 0.0f;
    }
    for (int j = i; j < wn; j += stride) wbf[j] = f2bf(W[j]);
}

__global__ __launch_bounds__(256)
void gemm_att_kernel(const float* __restrict__ X, const unsigned short* __restrict__ wbf,
                     const float* __restrict__ w_att, const int* __restrict__ dst,
                     unsigned short* __restrict__ h_bf, float* __restrict__ a_out,
                     float* __restrict__ segmax, int E) {
    __shared__ unsigned short lds_x[64 * LDSS];
    const int e0  = blockIdx.x * 64;
    const int tid = threadIdx.x;

    // Stage 64x192 fp32 tile -> bf16 LDS. 3072 float4 loads, 12 per thread, coalesced.
    const float4* Xv = (const float4*)(X + (size_t)e0 * KDIM);
    #pragma unroll
    for (int it = 0; it < 12; ++it) {
        int f = it * 256 + tid;         // float4 index in tile
        int e = f / 48;                 // 48 float4 per row
        int c = f - e * 48;
        float4 v;
        if (e0 + e < E) v = Xv[f];
        else            v = make_float4(0.f, 0.f, 0.f, 0.f);
        unsigned short* p = &lds_x[e * LDSS + c * 4];
        p[0] = f2bf(v.x); p[1] = f2bf(v.y); p[2] = f2bf(v.z); p[3] = f2bf(v.w);
    }
    __syncthreads();

    const int wave  = tid >> 6;
    const int lane  = tid & 63;
    const int n16   = lane & 15;      // col index within 16 (also A-row index)
    const int quad  = lane >> 4;      // K-chunk selector
    const int m0    = wave * 16;      // this wave's edge-tile base within block

    f32x4 acc[4] = {{0,0,0,0},{0,0,0,0},{0,0,0,0},{0,0,0,0}};
    #pragma unroll
    for (int kk = 0; kk < 6; ++kk) {
        // A[m = lane&15][k = kk*32 + quad*8 + j]
        bf16x8 afrag = *(const bf16x8*)&lds_x[(m0 + n16) * LDSS + kk * 32 + quad * 8];
        #pragma unroll
        for (int nt = 0; nt < 4; ++nt) {
            // B[k][n] = W[n][k]; lane&15 = n, k = kk*32 + quad*8 + j
            bf16x8 bfrag = *(const bf16x8*)&wbf[(nt * 16 + n16) * KDIM + kk * 32 + quad * 8];
            acc[nt] = __builtin_amdgcn_mfma_f32_16x16x32_bf16(afrag, bfrag, acc[nt], 0, 0, 0);
        }
    }

    // Epilogue: store h (bf16) and compute attention logit partials.
    // C/D layout: col = lane&15, row = quad*4 + reg.
    float wa[4];
    #pragma unroll
    for (int nt = 0; nt < 4; ++nt) wa[nt] = w_att[nt * 16 + n16];

    float pa[4] = {0.f, 0.f, 0.f, 0.f};
    #pragma unroll
    for (int nt = 0; nt < 4; ++nt) {
        #pragma unroll
        for (int r = 0; r < 4; ++r) {
            int erow = m0 + quad * 4 + r;
            int e    = e0 + erow;
            float v  = acc[nt][r];
            if (e < E) h_bf[(size_t)e * 64 + nt * 16 + n16] = f2bf(v);
            pa[r] += v * wa[nt];
        }
    }
    // Reduce across the 16 cols (lanes with same quad).
    #pragma unroll
    for (int r = 0; r < 4; ++r) {
        float s = pa[r];
        s += __shfl_xor(s, 1);
        s += __shfl_xor(s, 2);
        s += __shfl_xor(s, 4);
        s += __shfl_xor(s, 8);
        pa[r] = s;
    }
    if (n16 == 0) {
        #pragma unroll
        for (int r = 0; r < 4; ++r) {
            int e = e0 + m0 + quad * 4 + r;
            if (e >= E) continue;
            float x = pa[r];
            float mv;
            if (x > 15.0f) {
                mv = x;  // tanh(softplus(x)) == 1 to fp32 precision
            } else {
                float ex = expf(x);
                float t  = (1.0f + ex);
                t = t * t;
                mv = x * (t - 1.0f) / (t + 1.0f);   // x * tanh(log1p(exp(x)))
            }
            a_out[e] = mv;
            int d = dst[e];
            if (mv >= 0.0f) atomicMax((int*)&segmax[d], __float_as_int(mv));
            else            atomicMin((unsigned*)&segmax[d], __float_as_uint(mv));
        }
    }
}

__global__ __launch_bounds__(256)
void exp_denom_kernel(float* __restrict__ a, const int* __restrict__ dst,
                      const float* __restrict__ segmax, float* __restrict__ denom, int E) {
    int i = blockIdx.x * blockDim.x + threadIdx.x;
    if (i < E) {
        int d = dst[i];
        float ev = expf(a[i] - segmax[d]);
        a[i] = ev;
        atomicAdd(&denom[d], ev);
    }
}

__global__ __launch_bounds__(256)
void aggregate_kernel(const unsigned short* __restrict__ h_bf, const float* __restrict__ a,
                      const float* __restrict__ denom, const int* __restrict__ dst,
                      float* __restrict__ out, int E) {
    int gw   = (int)((blockIdx.x * (unsigned)blockDim.x + threadIdx.x) >> 6);  // global wave = edge
    int lane = threadIdx.x & 63;
    if (gw >= E) return;
    int   d = dst[gw];
    float p = a[gw] / denom[d];
    float hv = bf2f(h_bf[(size_t)gw * 64 + lane]);
    atomicAdd(&out[(size_t)d * 64 + lane], hv * p);
}

extern "C" void kernel_launch(void* const* d_in, const int* in_sizes, int n_in,
                              void* d_out, int out_size, void* d_ws, size_t ws_size,
                              hipStream_t stream) {
    const float* X     = (const float*)d_in[0];
    const int*   idx   = (const int*)d_in[1];
    const float* W     = (const float*)d_in[2];
    const float* w_att = (const float*)d_in[3];

    const int E       = in_sizes[1] / 2;     // indices are [2, E]
    const int n_nodes = out_size / 64;       // D_OUT = 64
    const int wn      = in_sizes[2];         // 64*192 = 12288
    const int* dst    = idx;                 // row 0 of indices

    // Workspace layout (16B-aligned chunks):
    char* ws = (char*)d_ws;
    unsigned short* wbf  = (unsigned short*)ws;                    // 24576 B
    unsigned short* h_bf = (unsigned short*)(ws + 24576);          // E*64*2 B
    size_t off = 24576 + (size_t)E * 64 * 2;
    float* a      = (float*)(ws + off);      off += (size_t)E * 4;
    float* segmax = (float*)(ws + off);      off += (size_t)n_nodes * 4;
    float* denom  = (float*)(ws + off);

    float* out = (float*)d_out;

    init_kernel<<<1024, 256, 0, stream>>>(out, out_size, segmax, denom, n_nodes, W, wbf, wn);

    int nblk_gemm = (E + 63) / 64;
    gemm_att_kernel<<<nblk_gemm, 256, 0, stream>>>(X, wbf, w_att, dst, h_bf, a, segmax, E);

    int nblk_exp = (E + 255) / 256;
    exp_denom_kernel<<<nblk_exp, 256, 0, stream>>>(a, dst, segmax, denom, E);

    int nblk_agg = (E + 3) / 4;   // 4 waves (edges) per 256-thread block
    aggregate_kernel<<<nblk_agg, 256, 0, stream>>>(h_bf, a, denom, dst, out, E);
}

// Round 2
// 1058.977 us; speedup vs baseline: 1.0604x; 1.0604x over previous
//
#include <hip/hip_runtime.h>
#include <hip/hip_bf16.h>
#include <math.h>

// Pipeline (E=800000, IN_DIM=192, D_OUT=64, N=out_size/64=50000):
//   K0 init:     count=0, cursor=0, W fp32->bf16
//   K1 gemm_att: h = X @ W^T via bf16 MFMA, a[e] = mish(h . w_att),
//                count[dst[e]]++  (atomic, 50k counters — cheap)
//   K2 scan:     offsets = exclusive_scan(count)   (3 tiny kernels)
//   K3 scatter:  perm = edges sorted by dst (counting-sort placement)
//   K4 aggregate: per node (one wave): m=max a; acc=sum exp(a-m)*h; s=sum exp;
//                out[n,:] = acc/s  — zero atomics on out, one write per row.

typedef __bf16  bf16x8 __attribute__((ext_vector_type(8)));
typedef float   f32x4  __attribute__((ext_vector_type(4)));

#define KDIM 192
#define LDSS 200   // LDS row stride in bf16 units (padded)

__device__ inline unsigned short f2bf(float f) {
    unsigned u = __float_as_uint(f);
    unsigned r = u + 0x7fffu + ((u >> 16) & 1u);   // round-to-nearest-even
    return (unsigned short)(r >> 16);
}
__device__ inline float bf2f(unsigned short h) {
    return __uint_as_float(((unsigned)h) << 16);
}

__global__ void init_kernel(int* __restrict__ count, int* __restrict__ cursor, int n_nodes,
                            const float* __restrict__ W, unsigned short* __restrict__ wbf, int wn) {
    int i = blockIdx.x * blockDim.x + threadIdx.x;
    int stride = gridDim.x * blockDim.x;
    for (int j = i; j < n_nodes; j += stride) { count[j] = 0; cursor[j] = 0; }
    for (int j = i; j < wn; j += stride) wbf[j] = f2bf(W[j]);
}

__global__ __launch_bounds__(256)
void gemm_att_kernel(const float* __restrict__ X, const unsigned short* __restrict__ wbf,
                     const float* __restrict__ w_att, const int* __restrict__ dst,
                     unsigned short* __restrict__ h_bf, float* __restrict__ a_out,
                     int* __restrict__ count, int E) {
    __shared__ unsigned short lds_x[64 * LDSS];
    const int e0  = blockIdx.x * 64;
    const int tid = threadIdx.x;

    // Stage 64x192 fp32 tile -> bf16 LDS. Coalesced float4, 12 per thread.
    const float4* Xv = (const float4*)(X + (size_t)e0 * KDIM);
    #pragma unroll
    for (int it = 0; it < 12; ++it) {
        int f = it * 256 + tid;         // float4 index in tile
        int e = f / 48;                 // 48 float4 per row
        int c = f - e * 48;
        float4 v;
        if (e0 + e < E) v = Xv[f];
        else            v = make_float4(0.f, 0.f, 0.f, 0.f);
        unsigned short* p = &lds_x[e * LDSS + c * 4];
        p[0] = f2bf(v.x); p[1] = f2bf(v.y); p[2] = f2bf(v.z); p[3] = f2bf(v.w);
    }
    __syncthreads();

    const int wave  = tid >> 6;
    const int lane  = tid & 63;
    const int n16   = lane & 15;
    const int quad  = lane >> 4;
    const int m0    = wave * 16;

    f32x4 acc[4] = {{0,0,0,0},{0,0,0,0},{0,0,0,0},{0,0,0,0}};
    #pragma unroll
    for (int kk = 0; kk < 6; ++kk) {
        bf16x8 afrag = *(const bf16x8*)&lds_x[(m0 + n16) * LDSS + kk * 32 + quad * 8];
        #pragma unroll
        for (int nt = 0; nt < 4; ++nt) {
            bf16x8 bfrag = *(const bf16x8*)&wbf[(nt * 16 + n16) * KDIM + kk * 32 + quad * 8];
            acc[nt] = __builtin_amdgcn_mfma_f32_16x16x32_bf16(afrag, bfrag, acc[nt], 0, 0, 0);
        }
    }

    // Epilogue: store h (bf16) and attention logit partials.
    // C/D layout: col = lane&15, row = quad*4 + reg.
    float wa[4];
    #pragma unroll
    for (int nt = 0; nt < 4; ++nt) wa[nt] = w_att[nt * 16 + n16];

    float pa[4] = {0.f, 0.f, 0.f, 0.f};
    #pragma unroll
    for (int nt = 0; nt < 4; ++nt) {
        #pragma unroll
        for (int r = 0; r < 4; ++r) {
            int e = e0 + m0 + quad * 4 + r;
            float v = acc[nt][r];
            if (e < E) h_bf[(size_t)e * 64 + nt * 16 + n16] = f2bf(v);
            pa[r] += v * wa[nt];
        }
    }
    #pragma unroll
    for (int r = 0; r < 4; ++r) {
        float s = pa[r];
        s += __shfl_xor(s, 1);
        s += __shfl_xor(s, 2);
        s += __shfl_xor(s, 4);
        s += __shfl_xor(s, 8);
        pa[r] = s;
    }
    if (n16 == 0) {
        #pragma unroll
        for (int r = 0; r < 4; ++r) {
            int e = e0 + m0 + quad * 4 + r;
            if (e >= E) continue;
            float x = pa[r];
            float mv;
            if (x > 15.0f) {
                mv = x;
            } else {
                float ex = expf(x);
                float t  = (1.0f + ex);
                t = t * t;
                mv = x * (t - 1.0f) / (t + 1.0f);   // x * tanh(softplus(x))
            }
            a_out[e] = mv;
            atomicAdd(&count[dst[e]], 1);
        }
    }
}

// ---- scan (exclusive) over count[n] -> offsets, 3 tiny kernels ----
__global__ __launch_bounds__(256)
void scan1_kernel(const int* __restrict__ count, int* __restrict__ offsets,
                  int* __restrict__ bsum, int n) {
    __shared__ int tmp[256];
    int i = blockIdx.x * 256 + threadIdx.x;
    int v = (i < n) ? count[i] : 0;
    tmp[threadIdx.x] = v;
    __syncthreads();
    #pragma unroll
    for (int off = 1; off < 256; off <<= 1) {
        int t = (threadIdx.x >= off) ? tmp[threadIdx.x - off] : 0;
        __syncthreads();
        tmp[threadIdx.x] += t;
        __syncthreads();
    }
    if (i < n) offsets[i] = tmp[threadIdx.x] - v;   // exclusive
    if (threadIdx.x == 255) bsum[blockIdx.x] = tmp[255];
}

__global__ __launch_bounds__(256)
void scan2_kernel(int* __restrict__ bsum, int nb) {
    __shared__ int tmp[256];
    int v = (threadIdx.x < nb) ? bsum[threadIdx.x] : 0;
    tmp[threadIdx.x] = v;
    __syncthreads();
    #pragma unroll
    for (int off = 1; off < 256; off <<= 1) {
        int t = (threadIdx.x >= off) ? tmp[threadIdx.x - off] : 0;
        __syncthreads();
        tmp[threadIdx.x] += t;
        __syncthreads();
    }
    if (threadIdx.x < nb) bsum[threadIdx.x] = tmp[threadIdx.x] - v;  // exclusive
}

__global__ __launch_bounds__(256)
void scan3_kernel(int* __restrict__ offsets, const int* __restrict__ bsum, int n, int E) {
    int i = blockIdx.x * 256 + threadIdx.x;
    if (i < n) offsets[i] += bsum[blockIdx.x];
    if (i == 0) offsets[n] = E;
}

__global__ __launch_bounds__(256)
void scatter_kernel(const int* __restrict__ dst, const int* __restrict__ offsets,
                    int* __restrict__ cursor, int* __restrict__ perm, int E) {
    int e = blockIdx.x * 256 + threadIdx.x;
    if (e < E) {
        int d = dst[e];
        int pos = offsets[d] + atomicAdd(&cursor[d], 1);
        perm[pos] = e;
    }
}

__global__ __launch_bounds__(256)
void aggregate_kernel(const unsigned short* __restrict__ h_bf, const float* __restrict__ a,
                      const int* __restrict__ perm, const int* __restrict__ offsets,
                      float* __restrict__ out, int N) {
    int node = (int)((blockIdx.x * (unsigned)blockDim.x + threadIdx.x) >> 6);
    int lane = threadIdx.x & 63;
    if (node >= N) return;
    int start = offsets[node];
    int end   = offsets[node + 1];
    if (start == end) { out[(size_t)node * 64 + lane] = 0.0f; return; }

    // pass 1: segment max (lane-parallel over edges, then wave-reduce)
    float m = -INFINITY;
    for (int i = start + lane; i < end; i += 64) m = fmaxf(m, a[perm[i]]);
    #pragma unroll
    for (int s = 32; s >= 1; s >>= 1) m = fmaxf(m, __shfl_xor(m, s));

    // pass 2: weighted sum; lane = output dim; scalar edge loop (broadcast loads)
    float acc = 0.0f, ssum = 0.0f;
    for (int i = start; i < end; ++i) {
        int e = perm[i];
        float w = __expf(a[e] - m);
        ssum += w;
        acc  += w * bf2f(h_bf[(size_t)e * 64 + lane]);
    }
    out[(size_t)node * 64 + lane] = acc / ssum;
}

extern "C" void kernel_launch(void* const* d_in, const int* in_sizes, int n_in,
                              void* d_out, int out_size, void* d_ws, size_t ws_size,
                              hipStream_t stream) {
    const float* X     = (const float*)d_in[0];
    const int*   idx   = (const int*)d_in[1];
    const float* W     = (const float*)d_in[2];
    const float* w_att = (const float*)d_in[3];

    const int E       = in_sizes[1] / 2;     // indices are [2, E]
    const int n_nodes = out_size / 64;       // D_OUT = 64
    const int wn      = in_sizes[2];         // 64*192
    const int* dst    = idx;                 // row 0 of indices

    // Workspace layout (16B-aligned chunks):
    char* ws = (char*)d_ws;
    unsigned short* wbf  = (unsigned short*)ws;                    // 24576 B
    unsigned short* h_bf = (unsigned short*)(ws + 24576);          // E*64*2
    size_t off = 24576 + (size_t)E * 64 * 2;
    float* a       = (float*)(ws + off);  off += (size_t)E * 4;
    int*   perm    = (int*)(ws + off);    off += (size_t)E * 4;
    int*   count   = (int*)(ws + off);    off += (size_t)n_nodes * 4;
    int*   cursor  = (int*)(ws + off);    off += (size_t)n_nodes * 4;
    int*   offsets = (int*)(ws + off);    off += (size_t)(n_nodes + 1) * 4;
    int*   bsum    = (int*)(ws + off);

    float* out = (float*)d_out;

    init_kernel<<<256, 256, 0, stream>>>(count, cursor, n_nodes, W, wbf, wn);

    int nblk_gemm = (E + 63) / 64;
    gemm_att_kernel<<<nblk_gemm, 256, 0, stream>>>(X, wbf, w_att, dst, h_bf, a, count, E);

    int nb = (n_nodes + 255) / 256;   // 196 for N=50000 (fits single-block scan2)
    scan1_kernel<<<nb, 256, 0, stream>>>(count, offsets, bsum, n_nodes);
    scan2_kernel<<<1, 256, 0, stream>>>(bsum, nb);
    scan3_kernel<<<nb, 256, 0, stream>>>(offsets, bsum, n_nodes, E);

    scatter_kernel<<<(E + 255) / 256, 256, 0, stream>>>(dst, offsets, cursor, perm, E);

    int nblk_agg = (n_nodes + 3) / 4;   // 4 waves (nodes) per 256-thread block
    aggregate_kernel<<<nblk_agg, 256, 0, stream>>>(h_bf, a, perm, offsets, out, n_nodes);
}